// Round 1
// baseline (1164.540 us; speedup 1.0000x reference)
//
#include <hip/hip_runtime.h>

typedef unsigned short u16;
typedef __attribute__((ext_vector_type(8))) short bf16x8;
typedef __attribute__((ext_vector_type(4))) float f32x4;

#define MFMA16(a, b, c) __builtin_amdgcn_mfma_f32_16x16x32_bf16((a), (b), (c), 0, 0, 0)

// ---- problem sizes ----
#define TT 128
#define BB 128
#define IN_ 512
#define HH 512
#define G4 2048   // 4*H
#define OUTD 512
#define TB 16384  // T*B

__device__ __forceinline__ u16 f2bf(float f) {
    union { float f; unsigned u; } v; v.f = f;
    unsigned r = v.u + 0x7FFFu + ((v.u >> 16) & 1u);
    return (u16)(r >> 16);
}
__device__ __forceinline__ float bf2f(u16 h) {
    union { unsigned u; float f; } v; v.u = ((unsigned)h) << 16; return v.f;
}
__device__ __forceinline__ float sigmoid_f(float x) { return 1.f / (1.f + __expf(-x)); }
__device__ __forceinline__ float tanh_f(float x) {
    float e = __expf(2.f * x);
    return 1.f - 2.f / (e + 1.f);
}

// ---- fp32 -> bf16 convert (vectorized) ----
__global__ void cvt_kernel(const float* __restrict__ src, u16* __restrict__ dst, int n4) {
    int i = blockIdx.x * blockDim.x + threadIdx.x;
    int stride = gridDim.x * blockDim.x;
    for (; i < n4; i += stride) {
        float4 v = ((const float4*)src)[i];
        ushort4 o;
        o.x = f2bf(v.x); o.y = f2bf(v.y); o.z = f2bf(v.z); o.w = f2bf(v.w);
        ((ushort4*)dst)[i] = o;
    }
}

__global__ void bias_kernel(const float* __restrict__ bihf, const float* __restrict__ bhhf,
                            float* __restrict__ bf_, const float* __restrict__ bihb,
                            const float* __restrict__ bhhb, float* __restrict__ bb_, int n) {
    int i = blockIdx.x * blockDim.x + threadIdx.x;
    if (i < n) {
        bf_[i] = bihf[i] + bhhf[i];
        bb_[i] = bihb[i] + bhhb[i];
    }
}

// ---- generic 128x128-tile bf16 MFMA GEMM: C[M,N] = A[M,K] * W[N,K]^T + bias[N] ----
// A, W row-major bf16 (u16 bits). Out: bf16 (flag=1) or fp32 (flag=0).
// Requires M%128==0, N%128==0, K%64==0.
__global__ __launch_bounds__(256) void gemm_bias_kernel(
    const u16* __restrict__ A, const u16* __restrict__ W,
    const float* __restrict__ bias, void* __restrict__ Cout,
    int M, int N, int K, int out_is_bf16) {
    // LDS tiles: 128 rows x 64 (BK) bf16, padded row stride 72 shorts (144B; 2-way banks = free)
    __shared__ __align__(16) u16 lA[128 * 72];
    __shared__ __align__(16) u16 lB[128 * 72];
    const int tid = threadIdx.x;
    const int m0 = blockIdx.x * 128;
    const int n0 = blockIdx.y * 128;
    const int wave = tid >> 6, lane = tid & 63;
    const int wm = wave >> 1, wn = wave & 1;   // 2x2 wave grid, each wave 64x64
    const int lrow = lane & 15, lq = lane >> 4;

    f32x4 acc[4][4] = {};

    for (int kc = 0; kc < K; kc += 64) {
        // stage A and B tiles: 128 rows x 128B each; 1024 x 16B chunks per tile
        #pragma unroll
        for (int i = 0; i < 4; ++i) {
            int c = i * 256 + tid;
            int row = c >> 3, off = c & 7;             // off: 16B units within 128B row
            *(uint4*)(&lA[row * 72 + off * 8]) =
                *(const uint4*)(&A[(size_t)(m0 + row) * K + kc + off * 8]);
            *(uint4*)(&lB[row * 72 + off * 8]) =
                *(const uint4*)(&W[(size_t)(n0 + row) * K + kc + off * 8]);
        }
        __syncthreads();
        #pragma unroll
        for (int ks = 0; ks < 2; ++ks) {
            bf16x8 af[4], bfr[4];
            #pragma unroll
            for (int mf = 0; mf < 4; ++mf)
                af[mf] = *(const bf16x8*)(&lA[(wm * 64 + mf * 16 + lrow) * 72 + ks * 32 + lq * 8]);
            #pragma unroll
            for (int nf = 0; nf < 4; ++nf)
                bfr[nf] = *(const bf16x8*)(&lB[(wn * 64 + nf * 16 + lrow) * 72 + ks * 32 + lq * 8]);
            #pragma unroll
            for (int mf = 0; mf < 4; ++mf)
                #pragma unroll
                for (int nf = 0; nf < 4; ++nf)
                    acc[mf][nf] = MFMA16(af[mf], bfr[nf], acc[mf][nf]);
        }
        __syncthreads();
    }

    // epilogue: D layout col=lane&15, row=(lane>>4)*4+reg
    #pragma unroll
    for (int mf = 0; mf < 4; ++mf) {
        #pragma unroll
        for (int nf = 0; nf < 4; ++nf) {
            int row = m0 + wm * 64 + mf * 16 + lq * 4;
            int col = n0 + wn * 64 + nf * 16 + lrow;
            float bv = bias[col];
            f32x4 v = acc[mf][nf];
            #pragma unroll
            for (int r = 0; r < 4; ++r) {
                float val = v[r] + bv;
                if (out_is_bf16)
                    ((u16*)Cout)[(size_t)(row + r) * N + col] = f2bf(val);
                else
                    ((float*)Cout)[(size_t)(row + r) * N + col] = val;
            }
        }
    }
}

// ---- one LSTM timestep, both directions ----
// grid = 256 blocks: bx = dir*128 + bt*16 + jt   (bt: 8 batch tiles of 16, jt: 16 j tiles of 32)
// Each block: gates tile [16 batch x (4 gates x 32 j)], K=512 over h_prev.
// wave w computes gate w (W_hh rows w*512 + j0 .. +32).
__global__ __launch_bounds__(256) void lstm_step_kernel(
    const u16* __restrict__ xw_f, const u16* __restrict__ xw_b,
    const u16* __restrict__ whh_f, const u16* __restrict__ whh_b,
    u16* __restrict__ hcat, float* __restrict__ c_f, float* __restrict__ c_b,
    int s) {
    const int bx = blockIdx.x;
    const int dir = bx >> 7;
    const int bt = (bx >> 4) & 7;
    const int jt = bx & 15;
    const u16* __restrict__ xw = dir ? xw_b : xw_f;
    const u16* __restrict__ whh = dir ? whh_b : whh_f;
    float* __restrict__ cst = dir ? c_b : c_f;
    const int t = dir ? (TT - 1 - s) : s;
    const int tprev = dir ? (t + 1) : (t - 1);
    const int b0 = bt * 16;
    const int j0 = jt * 32;

    __shared__ __align__(16) u16 lh[16 * 520];       // h_prev tile [16 x 512], stride 520 (1040B: 2-way banks)
    __shared__ float sgate[4][16][33];               // gate exchange [gate][b][j]

    const int tid = threadIdx.x;
    const int wave = tid >> 6, lane = tid & 63;
    const int lrow = lane & 15, lq = lane >> 4;

    f32x4 acc[2] = {};

    if (s > 0) {
        // stage h_prev [16 rows x 512 bf16] from hcat
        const u16* hsrc = hcat + ((size_t)tprev * BB + b0) * (2 * HH) + dir * HH;
        #pragma unroll
        for (int i = 0; i < 4; ++i) {
            int c = i * 256 + tid;          // 1024 chunks of 16B
            int row = c >> 6, off = c & 63;
            *(uint4*)(&lh[row * 520 + off * 8]) =
                *(const uint4*)(&hsrc[(size_t)row * (2 * HH) + off * 8]);
        }
        __syncthreads();
        const u16* wrow = whh + ((size_t)wave * HH + j0) * HH;  // 32 W rows for this wave's gate
        #pragma unroll 4
        for (int kc = 0; kc < 16; ++kc) {
            bf16x8 a = *(const bf16x8*)(&lh[lrow * 520 + kc * 32 + lq * 8]);
            bf16x8 w0 = *(const bf16x8*)(&wrow[(size_t)lrow * HH + kc * 32 + lq * 8]);
            bf16x8 w1 = *(const bf16x8*)(&wrow[(size_t)(16 + lrow) * HH + kc * 32 + lq * 8]);
            acc[0] = MFMA16(a, w0, acc[0]);
            acc[1] = MFMA16(a, w1, acc[1]);
        }
    }

    // gates -> LDS (D layout: m = lq*4+r is batch-local, n = nf*16+lrow is j-local)
    #pragma unroll
    for (int nf = 0; nf < 2; ++nf)
        #pragma unroll
        for (int r = 0; r < 4; ++r)
            sgate[wave][lq * 4 + r][nf * 16 + lrow] = acc[nf][r];
    __syncthreads();

    // pointwise: 16x32 = 512 cells, 2 per thread
    for (int p = tid; p < 512; p += 256) {
        int bl = p >> 5, j = p & 31;
        int bg = b0 + bl;
        int jg = j0 + j;
        size_t xwbase = ((size_t)t * BB + bg) * G4 + jg;
        float gi = sgate[0][bl][j] + bf2f(xw[xwbase + 0 * HH]);
        float gf = sgate[1][bl][j] + bf2f(xw[xwbase + 1 * HH]);
        float gg = sgate[2][bl][j] + bf2f(xw[xwbase + 2 * HH]);
        float go = sgate[3][bl][j] + bf2f(xw[xwbase + 3 * HH]);
        float iv = sigmoid_f(gi);
        float fv = sigmoid_f(gf);
        float gv = tanh_f(gg);
        float ov = sigmoid_f(go);
        size_t cidx = (size_t)bg * HH + jg;
        float cprev = (s > 0) ? cst[cidx] : 0.f;
        float cn = fv * cprev + iv * gv;
        cst[cidx] = cn;
        float hn = ov * tanh_f(cn);
        hcat[((size_t)t * BB + bg) * (2 * HH) + dir * HH + jg] = f2bf(hn);
    }
}

// ---- workspace layout (bytes) ----
#define OFF_XBF    ((size_t)0)                         // 16384*512*2   = 16,777,216
#define OFF_WIHF   (OFF_XBF  + (size_t)TB * IN_ * 2)   //  2,097,152
#define OFF_WIHB   (OFF_WIHF + (size_t)G4 * IN_ * 2)
#define OFF_WHHF   (OFF_WIHB + (size_t)G4 * IN_ * 2)
#define OFF_WHHB   (OFF_WHHF + (size_t)G4 * HH * 2)
#define OFF_WLIN   (OFF_WHHB + (size_t)G4 * HH * 2)    //   512*1024*2
#define OFF_BIASF  (OFF_WLIN + (size_t)OUTD * 2 * HH * 2)
#define OFF_BIASB  (OFF_BIASF + (size_t)G4 * 4)
#define OFF_XWF    (OFF_BIASB + (size_t)G4 * 4)        // 16384*2048*2  = 67,108,864
#define OFF_XWB    (OFF_XWF  + (size_t)TB * G4 * 2)
#define OFF_HCAT   (OFF_XWB  + (size_t)TB * G4 * 2)    // 16384*1024*2  = 33,554,432
#define OFF_CF     (OFF_HCAT + (size_t)TB * 2 * HH * 2)
#define OFF_CB     (OFF_CF   + (size_t)BB * HH * 4)
#define WS_NEED    (OFF_CB   + (size_t)BB * HH * 4)    // ~194.5 MB

extern "C" void kernel_launch(void* const* d_in, const int* in_sizes, int n_in,
                              void* d_out, int out_size, void* d_ws, size_t ws_size,
                              hipStream_t stream) {
    (void)in_sizes; (void)n_in; (void)out_size;
    if (ws_size < WS_NEED) return;  // workspace too small: cannot run

    const float* x    = (const float*)d_in[0];
    const float* Wihf = (const float*)d_in[1];
    const float* Whhf = (const float*)d_in[2];
    const float* bihf = (const float*)d_in[3];
    const float* bhhf = (const float*)d_in[4];
    const float* Wihb = (const float*)d_in[5];
    const float* Whhb = (const float*)d_in[6];
    const float* bihb = (const float*)d_in[7];
    const float* bhhb = (const float*)d_in[8];
    const float* Wlin = (const float*)d_in[9];
    const float* blin = (const float*)d_in[10];
    float* out = (float*)d_out;

    char* ws = (char*)d_ws;
    u16* x_bf    = (u16*)(ws + OFF_XBF);
    u16* wihf_bf = (u16*)(ws + OFF_WIHF);
    u16* wihb_bf = (u16*)(ws + OFF_WIHB);
    u16* whhf_bf = (u16*)(ws + OFF_WHHF);
    u16* whhb_bf = (u16*)(ws + OFF_WHHB);
    u16* wlin_bf = (u16*)(ws + OFF_WLIN);
    float* bias_f = (float*)(ws + OFF_BIASF);
    float* bias_b = (float*)(ws + OFF_BIASB);
    u16* xw_f = (u16*)(ws + OFF_XWF);
    u16* xw_b = (u16*)(ws + OFF_XWB);
    u16* hcat = (u16*)(ws + OFF_HCAT);
    float* c_f = (float*)(ws + OFF_CF);
    float* c_b = (float*)(ws + OFF_CB);

    // prep: convert to bf16, sum biases
    cvt_kernel<<<2048, 256, 0, stream>>>(x, x_bf, (TB * IN_) / 4);
    cvt_kernel<<<512, 256, 0, stream>>>(Wihf, wihf_bf, (G4 * IN_) / 4);
    cvt_kernel<<<512, 256, 0, stream>>>(Wihb, wihb_bf, (G4 * IN_) / 4);
    cvt_kernel<<<512, 256, 0, stream>>>(Whhf, whhf_bf, (G4 * HH) / 4);
    cvt_kernel<<<512, 256, 0, stream>>>(Whhb, whhb_bf, (G4 * HH) / 4);
    cvt_kernel<<<512, 256, 0, stream>>>(Wlin, wlin_bf, (OUTD * 2 * HH) / 4);
    bias_kernel<<<8, 256, 0, stream>>>(bihf, bhhf, bias_f, bihb, bhhb, bias_b, G4);

    // phase 1: xw = x @ W_ih^T + (b_ih + b_hh), bf16 out
    gemm_bias_kernel<<<dim3(TB / 128, G4 / 128), 256, 0, stream>>>(
        x_bf, wihf_bf, bias_f, xw_f, TB, G4, IN_, 1);
    gemm_bias_kernel<<<dim3(TB / 128, G4 / 128), 256, 0, stream>>>(
        x_bf, wihb_bf, bias_b, xw_b, TB, G4, IN_, 1);

    // phase 2: 128 recurrent steps, both directions per launch
    for (int s = 0; s < TT; ++s)
        lstm_step_kernel<<<256, 256, 0, stream>>>(xw_f, xw_b, whhf_bf, whhb_bf,
                                                  hcat, c_f, c_b, s);

    // phase 3: out = hcat @ W_lin^T + b_lin, fp32 out
    gemm_bias_kernel<<<dim3(TB / 128, OUTD / 128), 256, 0, stream>>>(
        hcat, wlin_bf, blin, out, TB, OUTD, 2 * HH, 0);
}